// Round 12
// baseline (198.098 us; speedup 1.0000x reference)
//
#include <hip/hip_runtime.h>
#include <math.h>

#define NSEQ 2048
#define CDIM 768
#define NH   12
#define HD   64
#define NB   2

typedef unsigned short u16;
typedef __attribute__((ext_vector_type(8))) short bf16x8;   // 8 bf16 = 4 VGPRs
typedef __attribute__((ext_vector_type(4))) float f32x4;
typedef __attribute__((ext_vector_type(4))) unsigned short ushort4v;
typedef __attribute__((ext_vector_type(8))) unsigned short ushort8;

// fp32 -> bf16 round-to-nearest-even (no NaN inputs here)
__device__ __forceinline__ u16 f2bf(float x) {
    unsigned int u = __float_as_uint(x);
    u += 0x7fffu + ((u >> 16) & 1u);
    return (u16)(u >> 16);
}

// pack 8 fp32 (two float4) -> 8 bf16 in a uint4
__device__ __forceinline__ uint4 pack8(float4 a, float4 b) {
    union { ushort8 s; uint4 u; } o;
    o.s[0] = f2bf(a.x); o.s[1] = f2bf(a.y);
    o.s[2] = f2bf(a.z); o.s[3] = f2bf(a.w);
    o.s[4] = f2bf(b.x); o.s[5] = f2bf(b.y);
    o.s[6] = f2bf(b.z); o.s[7] = f2bf(b.w);
    return o.u;
}

#define LSTR 72   // LDS row stride (u16): +8 pad; 144B row -> 16B-aligned b128
#define PSTR 40   // P tile stride (u16): 32 keys + 8 pad; 80B, 16B-aligned

// ---------------------------------------------------------------------------
// Kernel 1: qkv = X @ Wqkv^T, bf16 MFMA, fp32 inputs converted in-register
// during staging. Tiles 128x128x64, 4 waves 2x2, wave 64x64 via 4x4 MFMA
// 16x16x32, register-prefetch staging, LDS epilogue with full-128B-line
// stores. Fused scale (q), RoPE (q,k).
// Q,K: [B,H,N,64]; V: [B,H,64,N] (transposed for attn B-fragments).
// ---------------------------------------------------------------------------
__global__ __launch_bounds__(256)
void qkv_mfma_kernel(const float* __restrict__ Xf, const float* __restrict__ Wf,
                     u16* __restrict__ Qb, u16* __restrict__ Kb,
                     u16* __restrict__ Vb)
{
    __shared__ __align__(16) u16 S[2 * 128 * LSTR];
    u16* As = S;
    u16* Bs = S + 128 * LSTR;

    const int tid  = threadIdx.x;
    const int lane = tid & 63;
    const int wid  = tid >> 6;
    const int l15  = lane & 15;
    const int quad = lane >> 4;
    const int wr = wid >> 1, wc = wid & 1;
    const int m0 = blockIdx.x * 128;
    const int n0 = blockIdx.y * 128;

    const int row = tid >> 3, c8s = (tid & 7) << 3;   // 8-u16 chunk coords

    f32x4 acc[4][4];
#pragma unroll
    for (int mi = 0; mi < 4; ++mi)
#pragma unroll
        for (int ni = 0; ni < 4; ++ni)
            acc[mi][ni] = (f32x4){0.f, 0.f, 0.f, 0.f};

    float4 pa[4][2], pb[4][2];
#pragma unroll
    for (int it = 0; it < 4; ++it) {
        size_t ga = (size_t)(m0 + row + 32 * it) * CDIM + c8s;
        size_t gb = (size_t)(n0 + row + 32 * it) * CDIM + c8s;
        pa[it][0] = *(const float4*)&Xf[ga];
        pa[it][1] = *(const float4*)&Xf[ga + 4];
        pb[it][0] = *(const float4*)&Wf[gb];
        pb[it][1] = *(const float4*)&Wf[gb + 4];
    }

    for (int kt = 0; kt < CDIM; kt += 64) {
        __syncthreads();
#pragma unroll
        for (int it = 0; it < 4; ++it) {
            *(uint4*)&As[(row + 32 * it) * LSTR + c8s] =
                pack8(pa[it][0], pa[it][1]);
            *(uint4*)&Bs[(row + 32 * it) * LSTR + c8s] =
                pack8(pb[it][0], pb[it][1]);
        }
        __syncthreads();

        if (kt + 64 < CDIM) {
#pragma unroll
            for (int it = 0; it < 4; ++it) {
                size_t ga = (size_t)(m0 + row + 32 * it) * CDIM + kt + 64 + c8s;
                size_t gb = (size_t)(n0 + row + 32 * it) * CDIM + kt + 64 + c8s;
                pa[it][0] = *(const float4*)&Xf[ga];
                pa[it][1] = *(const float4*)&Xf[ga + 4];
                pb[it][0] = *(const float4*)&Wf[gb];
                pb[it][1] = *(const float4*)&Wf[gb + 4];
            }
        }

#pragma unroll
        for (int k = 0; k < 2; ++k) {
            bf16x8 af[4];
#pragma unroll
            for (int mi = 0; mi < 4; ++mi)
                af[mi] = *(const bf16x8*)
                    &As[(wr * 64 + mi * 16 + l15) * LSTR + quad * 8 + 32 * k];
#pragma unroll
            for (int ni = 0; ni < 4; ++ni) {
                bf16x8 bfr = *(const bf16x8*)
                    &Bs[(wc * 64 + ni * 16 + l15) * LSTR + quad * 8 + 32 * k];
#pragma unroll
                for (int mi = 0; mi < 4; ++mi)
                    acc[mi][ni] = __builtin_amdgcn_mfma_f32_16x16x32_bf16(
                        af[mi], bfr, acc[mi][ni], 0, 0, 0);
            }
        }
    }

    __syncthreads();   // all waves done reading As/Bs before overlay

    // Epilogue. C-layout: token row = wr*64+mi*16+quad*4+r,
    // feature col = wc*64+ni*16+l15. Wave's 64 cols = exactly one head.
    const int bi      = m0 >> 11;
    const int nbase   = (m0 & 2047) + wr * 64;
    const int colbase = n0 + wc * 64;
    const int sel     = colbase / CDIM;          // 0=q,1=k,2=v (wave-uniform)
    const int h       = (colbase % CDIM) >> 6;

    u16* Ew = S + wid * 64 * LSTR;     // wave-private 64x72 tile
    const int grow = lane >> 3;        // copy-out: 8 lanes cover one 128B row
    const int gc8  = (lane & 7) << 3;

    if (sel == 2) {
#pragma unroll
        for (int ni = 0; ni < 4; ++ni)
#pragma unroll
            for (int mi = 0; mi < 4; ++mi)
#pragma unroll
                for (int r = 0; r < 4; ++r)
                    Ew[(ni * 16 + l15) * LSTR + mi * 16 + quad * 4 + r] =
                        f2bf(acc[mi][ni][r]);
        u16* dst = Vb + (size_t)(bi * NH + h) * HD * NSEQ;   // [64][2048]
#pragma unroll
        for (int it = 0; it < 8; ++it) {
            int dd = grow + 8 * it;
            *(uint4*)&dst[(size_t)dd * NSEQ + nbase + gc8] =
                *(const uint4*)&Ew[dd * LSTR + gc8];
        }
    } else {
        u16* dst = ((sel == 0) ? Qb : Kb) + (size_t)(bi * NH + h) * NSEQ * HD;
        const float scl = (sel == 0) ? 0.125f : 1.0f;
#pragma unroll
        for (int ni = 0; ni < 4; ++ni) {
            int dd = ni * 16 + l15;
            float invf = expf(-0.14391156831212787f * (float)(dd & ~1));
#pragma unroll
            for (int mi = 0; mi < 4; ++mi) {
                f32x4 val = acc[mi][ni];
#pragma unroll
                for (int r = 0; r < 4; ++r) {
                    float e = val[r] * scl;
                    float p = __shfl_xor(e, 1);    // pair partner (col^1)
                    int n = nbase + mi * 16 + quad * 4 + r;
                    float sv, cv;
                    __sincosf((float)n * invf, &sv, &cv);
                    float o = (dd & 1) ? (e * cv + p * sv)
                                       : (e * cv - p * sv);
                    Ew[(mi * 16 + quad * 4 + r) * LSTR + dd] = f2bf(o);
                }
            }
        }
#pragma unroll
        for (int it = 0; it < 8; ++it) {
            int tr = grow + 8 * it;
            *(uint4*)&dst[(size_t)(nbase + tr) * HD + gc8] =
                *(const uint4*)&Ew[tr * LSTR + gc8];
        }
    }
}

// ---------------------------------------------------------------------------
// Kernel 2: flash attention, bf16 MFMA. 64 q-rows/block, 4 waves =
// 2 q-groups x 2 KEY-groups (each wave owns 32 keys of the 64-key tile).
// Fixed-max softmax makes key-split trivially correct: O and l are pure
// sums over keys -> one LDS exchange between key-group partners at the end.
// Wave's 32 keys = exactly one K=32 PV step (halves bv/ap reads); S^T has
// 2 mt tiles (halves ak reads). LDS 47.1 KB -> 3 blocks/CU; grid 32x24=768
// balanced 3/CU. (R11 compile fix: no __shared__ pointer arrays — gfx950
// rejects the addrspacecast initializer; use runtime offsets instead.)
// ---------------------------------------------------------------------------
__global__ __launch_bounds__(256)
void attn_kernel(const u16* __restrict__ Qb, const u16* __restrict__ Kb,
                 const u16* __restrict__ Vt, u16* __restrict__ AO)
{
    // layout: Ks buf0 | Ks buf1 | Vs buf0 | Vs buf1 (64x72 each) | P area
    __shared__ __align__(16) u16 S[4 * 64 * LSTR + 4 * 32 * PSTR];
    u16* Pa = S + 4 * 64 * LSTR;

    const int tid  = threadIdx.x;
    const int lane = tid & 63;
    const int wid  = tid >> 6;
    const int l15  = lane & 15;
    const int quad = lane >> 4;
    const int qg = wid >> 1;        // q-group: rows qg*32..qg*32+31
    const int kg = wid & 1;         // key-group: keys kg*32..kg*32+31
    const int qt = blockIdx.x;      // 0..31 (64 q-rows each)
    const int bh = blockIdx.y;      // 0..23

    const u16* Qg = Qb + ((size_t)bh * NSEQ + qt * 64) * HD;
    const u16* Kg = Kb + (size_t)bh * NSEQ * HD;
    const u16* Vg = Vt + (size_t)bh * HD * NSEQ;   // [64][2048]

    const int srow = tid >> 3, sc8 = (tid & 7) << 3;   // rows 0..31

    // stage Q (64x64) into Ks buffer 1 (free until kt=0's prefetch write);
    // stage K/V tile 0 into buffer 0
#pragma unroll
    for (int it = 0; it < 2; ++it) {
        int row = srow + 32 * it;
        *(uint4*)&S[(64 * LSTR) + row * LSTR + sc8] =
            *(const uint4*)&Qg[row * HD + sc8];
        *(uint4*)&S[row * LSTR + sc8] =
            *(const uint4*)&Kg[(size_t)row * HD + sc8];
        *(uint4*)&S[(2 * 64 * LSTR) + row * LSTR + sc8] =
            *(const uint4*)&Vg[(size_t)row * NSEQ + sc8];
    }
    __syncthreads();

    // loop-invariant Q B-frags (rows qg*32 + qf*16 + l15), from Ks buf 1
    bf16x8 aq[2][2];
#pragma unroll
    for (int qf = 0; qf < 2; ++qf)
#pragma unroll
        for (int k = 0; k < 2; ++k)
            aq[qf][k] = *(const bf16x8*)
                &S[(64 * LSTR) + (qg * 32 + qf * 16 + l15) * LSTR +
                   quad * 8 + 32 * k];
    __syncthreads();   // Q frags grabbed before buf 1 is overwritten

    float l_part[2] = {0.f, 0.f};
    f32x4 O[2][4];
#pragma unroll
    for (int qf = 0; qf < 2; ++qf)
#pragma unroll
        for (int t = 0; t < 4; ++t) O[qf][t] = (f32x4){0.f, 0.f, 0.f, 0.f};

    u16* Pw = Pa + wid * 32 * PSTR;   // wave-private 32q x 32key P tile

    for (int kt = 0; kt < NSEQ / 64; ++kt) {
        const int cur = kt & 1;
        u16* Kcur = S + cur * 64 * LSTR;
        u16* Vcur = S + (2 + cur) * 64 * LSTR;
        u16* Knxt = S + (cur ^ 1) * 64 * LSTR;
        u16* Vnxt = S + (2 + (cur ^ 1)) * 64 * LSTR;

        uint4 kpre[2], vpre[2];
        if (kt + 1 < NSEQ / 64) {
#pragma unroll
            for (int it = 0; it < 2; ++it) {
                int row = srow + 32 * it;
                kpre[it] = *(const uint4*)
                    &Kg[(size_t)((kt + 1) * 64 + row) * HD + sc8];
                vpre[it] = *(const uint4*)
                    &Vg[(size_t)row * NSEQ + (kt + 1) * 64 + sc8];
            }
        }

        // S^T = K . Q^T over this wave's 32 keys (2 mt tiles x 2 k-steps)
        f32x4 sacc[2][2];
#pragma unroll
        for (int qf = 0; qf < 2; ++qf)
#pragma unroll
            for (int mt = 0; mt < 2; ++mt)
                sacc[qf][mt] = (f32x4){0.f, 0.f, 0.f, 0.f};
#pragma unroll
        for (int k = 0; k < 2; ++k) {
#pragma unroll
            for (int mt = 0; mt < 2; ++mt) {
                bf16x8 ak = *(const bf16x8*)
                    &Kcur[(kg * 32 + mt * 16 + l15) * LSTR +
                          quad * 8 + 32 * k];
                sacc[0][mt] = __builtin_amdgcn_mfma_f32_16x16x32_bf16(
                    ak, aq[0][k], sacc[0][mt], 0, 0, 0);
                sacc[1][mt] = __builtin_amdgcn_mfma_f32_16x16x32_bf16(
                    ak, aq[1][k], sacc[1][mt], 0, 0, 0);
            }
        }

        // fixed-max softmax, in-lane; local key idx = mt*16+quad*4+r
#pragma unroll
        for (int qf = 0; qf < 2; ++qf) {
#pragma unroll
            for (int mt = 0; mt < 2; ++mt) {
                float e0 = __expf(sacc[qf][mt][0]);
                float e1 = __expf(sacc[qf][mt][1]);
                float e2 = __expf(sacc[qf][mt][2]);
                float e3 = __expf(sacc[qf][mt][3]);
                l_part[qf] += (e0 + e1) + (e2 + e3);
                ushort4v pk;
                pk.x = f2bf(e0); pk.y = f2bf(e1);
                pk.z = f2bf(e2); pk.w = f2bf(e3);
                *(ushort4v*)&Pw[(qf * 16 + l15) * PSTR + mt * 16 + quad * 4]
                    = pk;
            }
        }

        // O += P . V : single K=32 step over this wave's keys
#pragma unroll
        for (int qf = 0; qf < 2; ++qf) {
            bf16x8 ap = *(const bf16x8*)
                &Pw[(qf * 16 + l15) * PSTR + quad * 8];
#pragma unroll
            for (int t = 0; t < 4; ++t) {
                bf16x8 bv = *(const bf16x8*)
                    &Vcur[(t * 16 + l15) * LSTR + kg * 32 + quad * 8];
                O[qf][t] = __builtin_amdgcn_mfma_f32_16x16x32_bf16(
                    ap, bv, O[qf][t], 0, 0, 0);
            }
        }

        if (kt + 1 < NSEQ / 64) {
#pragma unroll
            for (int it = 0; it < 2; ++it) {
                int row = srow + 32 * it;
                *(uint4*)&Knxt[row * LSTR + sc8] = kpre[it];
                *(uint4*)&Vnxt[row * LSTR + sc8] = vpre[it];
            }
        }
        __syncthreads();   // single barrier per iteration
    }

    // quad-reduce l (per q-row, over this wave's keys)
    float lq[2];
#pragma unroll
    for (int qf = 0; qf < 2; ++qf) {
        float l = l_part[qf] + __shfl_xor(l_part[qf], 16);
        l += __shfl_xor(l, 32);
        lq[qf] = l;   // uniform across quads; indexed by l15 = q-row
    }

    // cross-key-group exchange: kg=1 writes partials, kg=0 combines+stores
    float* R = (float*)S;   // O slots: 1024 f32x4 (16 KB); l at float 4096+
    if (kg == 1) {
#pragma unroll
        for (int qf = 0; qf < 2; ++qf)
#pragma unroll
            for (int t = 0; t < 4; ++t)
                *(f32x4*)&R[(((qg * 8 + qf * 4 + t) * 64) + lane) * 4] =
                    O[qf][t];
        if (quad == 0) {
            R[4096 + (qg * 2 + 0) * 16 + l15] = lq[0];
            R[4096 + (qg * 2 + 1) * 16 + l15] = lq[1];
        }
    }
    __syncthreads();
    if (kg == 0) {
        const int b = bh / NH, h = bh % NH;
#pragma unroll
        for (int qf = 0; qf < 2; ++qf) {
            float lsum = lq[qf] + R[4096 + (qg * 2 + qf) * 16 + l15];
            float inv[4];
#pragma unroll
            for (int r = 0; r < 4; ++r)
                inv[r] = 1.0f / __shfl(lsum, quad * 4 + r);
#pragma unroll
            for (int t = 0; t < 4; ++t) {
                f32x4 part = *(const f32x4*)
                    &R[(((qg * 8 + qf * 4 + t) * 64) + lane) * 4];
#pragma unroll
                for (int r = 0; r < 4; ++r) {
                    size_t row = (size_t)b * NSEQ + qt * 64 + qg * 32 +
                                 qf * 16 + quad * 4 + r;
                    AO[row * CDIM + h * HD + t * 16 + l15] =
                        f2bf((O[qf][t][r] + part[r]) * inv[r]);
                }
            }
        }
    }
}

// ---------------------------------------------------------------------------
// Kernel 3: out = AO @ Wproj^T + bias, bf16 MFMA; Wproj read fp32 and
// converted during staging. Tiles 128x128x64, 4 waves 2x2.
// grid MUST be (32, 6): 768 cols / 128 per tile = 6 column tiles.
// ---------------------------------------------------------------------------
__global__ __launch_bounds__(256)
void proj_kernel(const u16* __restrict__ A, const float* __restrict__ Wf,
                 const float* __restrict__ bias, float* __restrict__ out)
{
    __shared__ __align__(16) u16 As[128 * LSTR];
    __shared__ __align__(16) u16 Bs[128 * LSTR];
    const int tid  = threadIdx.x;
    const int lane = tid & 63;
    const int wid  = tid >> 6;
    const int l15  = lane & 15;
    const int quad = lane >> 4;
    const int wr = wid >> 1, wc = wid & 1;
    const int m0 = blockIdx.x * 128;
    const int n0 = blockIdx.y * 128;

    f32x4 acc[4][4];
#pragma unroll
    for (int mi = 0; mi < 4; ++mi)
#pragma unroll
        for (int ni = 0; ni < 4; ++ni)
            acc[mi][ni] = (f32x4){0.f, 0.f, 0.f, 0.f};

    for (int kt = 0; kt < CDIM; kt += 64) {
        __syncthreads();
#pragma unroll
        for (int it = 0; it < 4; ++it) {
            int idx = tid + 256 * it;
            int row = idx >> 3, c8 = (idx & 7) << 3;
            *(uint4*)&As[row * LSTR + c8] =
                *(const uint4*)&A[(size_t)(m0 + row) * CDIM + kt + c8];
            size_t gb = (size_t)(n0 + row) * CDIM + kt + c8;
            float4 w0 = *(const float4*)&Wf[gb];
            float4 w1 = *(const float4*)&Wf[gb + 4];
            *(uint4*)&Bs[row * LSTR + c8] = pack8(w0, w1);
        }
        __syncthreads();
#pragma unroll
        for (int k = 0; k < 2; ++k) {
            bf16x8 af[4], bf[4];
#pragma unroll
            for (int mi = 0; mi < 4; ++mi)
                af[mi] = *(const bf16x8*)
                    &As[(wr * 64 + mi * 16 + l15) * LSTR + quad * 8 + 32 * k];
#pragma unroll
            for (int ni = 0; ni < 4; ++ni)
                bf[ni] = *(const bf16x8*)
                    &Bs[(wc * 64 + ni * 16 + l15) * LSTR + quad * 8 + 32 * k];
#pragma unroll
            for (int mi = 0; mi < 4; ++mi)
#pragma unroll
                for (int ni = 0; ni < 4; ++ni)
                    acc[mi][ni] = __builtin_amdgcn_mfma_f32_16x16x32_bf16(
                        af[mi], bf[ni], acc[mi][ni], 0, 0, 0);
        }
    }

#pragma unroll
    for (int ni = 0; ni < 4; ++ni) {
        int col = n0 + wc * 64 + ni * 16 + l15;
        float bb = bias[col];
#pragma unroll
        for (int mi = 0; mi < 4; ++mi) {
            int row = m0 + wr * 64 + mi * 16 + quad * 4;
#pragma unroll
            for (int r = 0; r < 4; ++r)
                out[(size_t)(row + r) * CDIM + col] = acc[mi][ni][r] + bb;
        }
    }
}

// ---------------------------------------------------------------------------
extern "C" void kernel_launch(void* const* d_in, const int* in_sizes, int n_in,
                              void* d_out, int out_size, void* d_ws,
                              size_t ws_size, hipStream_t stream)
{
    const float* X     = (const float*)d_in[0];   // [2, 2048, 768]
    const float* Wqkv  = (const float*)d_in[1];   // [2304, 768]
    const float* Wproj = (const float*)d_in[2];   // [768, 768]
    const float* bias  = (const float*)d_in[3];   // [768]
    float* out = (float*)d_out;                   // [2, 2048, 768]

    const size_t per_buf = (size_t)NB * NH * NSEQ * HD;   // 3145728
    u16* Qb  = (u16*)d_ws;
    u16* Kb  = Qb + per_buf;
    u16* Vb  = Kb + per_buf;                      // [B,H,64,N]
    u16* AOb = Vb + per_buf;                      // [4096, 768] bf16

    qkv_mfma_kernel<<<dim3(32, 18), 256, 0, stream>>>(X, Wqkv, Qb, Kb, Vb);
    attn_kernel<<<dim3(32, 24), 256, 0, stream>>>(Qb, Kb, Vb, AOb);
    proj_kernel<<<dim3(32, 6), 256, 0, stream>>>(AOb, Wproj, bias, out);
}

// Round 13
// 181.895 us; speedup vs baseline: 1.0891x; 1.0891x over previous
//
#include <hip/hip_runtime.h>
#include <math.h>

#define NSEQ 2048
#define CDIM 768
#define NH   12
#define HD   64
#define NB   2

typedef unsigned short u16;
typedef __attribute__((ext_vector_type(8))) short bf16x8;   // 8 bf16 = 4 VGPRs
typedef __attribute__((ext_vector_type(4))) float f32x4;
typedef __attribute__((ext_vector_type(4))) unsigned short ushort4v;
typedef __attribute__((ext_vector_type(8))) unsigned short ushort8;

// fp32 -> bf16 round-to-nearest-even (no NaN inputs here)
__device__ __forceinline__ u16 f2bf(float x) {
    unsigned int u = __float_as_uint(x);
    u += 0x7fffu + ((u >> 16) & 1u);
    return (u16)(u >> 16);
}

// pack 8 fp32 (two float4) -> 8 bf16 in a uint4
__device__ __forceinline__ uint4 pack8(float4 a, float4 b) {
    union { ushort8 s; uint4 u; } o;
    o.s[0] = f2bf(a.x); o.s[1] = f2bf(a.y);
    o.s[2] = f2bf(a.z); o.s[3] = f2bf(a.w);
    o.s[4] = f2bf(b.x); o.s[5] = f2bf(b.y);
    o.s[6] = f2bf(b.z); o.s[7] = f2bf(b.w);
    return o.u;
}

#define LSTR 72   // LDS row stride (u16): +8 pad; 144B row -> 16B-aligned b128

// ---------------------------------------------------------------------------
// Kernel 1: qkv = X @ Wqkv^T, bf16 MFMA, fp32 inputs converted in-register
// during staging. Tiles 128x128x64, 4 waves 2x2, wave 64x64 via 4x4 MFMA
// 16x16x32, register-prefetch staging, LDS epilogue with full-128B-line
// stores. Fused scale (q), RoPE (q,k).
// Q,K: [B,H,N,64]; V: [B,H,64,N] (transposed for attn B-fragments).
// ---------------------------------------------------------------------------
__global__ __launch_bounds__(256)
void qkv_mfma_kernel(const float* __restrict__ Xf, const float* __restrict__ Wf,
                     u16* __restrict__ Qb, u16* __restrict__ Kb,
                     u16* __restrict__ Vb)
{
    __shared__ __align__(16) u16 S[2 * 128 * LSTR];
    u16* As = S;
    u16* Bs = S + 128 * LSTR;

    const int tid  = threadIdx.x;
    const int lane = tid & 63;
    const int wid  = tid >> 6;
    const int l15  = lane & 15;
    const int quad = lane >> 4;
    const int wr = wid >> 1, wc = wid & 1;
    const int m0 = blockIdx.x * 128;
    const int n0 = blockIdx.y * 128;

    const int row = tid >> 3, c8s = (tid & 7) << 3;   // 8-u16 chunk coords

    f32x4 acc[4][4];
#pragma unroll
    for (int mi = 0; mi < 4; ++mi)
#pragma unroll
        for (int ni = 0; ni < 4; ++ni)
            acc[mi][ni] = (f32x4){0.f, 0.f, 0.f, 0.f};

    float4 pa[4][2], pb[4][2];
#pragma unroll
    for (int it = 0; it < 4; ++it) {
        size_t ga = (size_t)(m0 + row + 32 * it) * CDIM + c8s;
        size_t gb = (size_t)(n0 + row + 32 * it) * CDIM + c8s;
        pa[it][0] = *(const float4*)&Xf[ga];
        pa[it][1] = *(const float4*)&Xf[ga + 4];
        pb[it][0] = *(const float4*)&Wf[gb];
        pb[it][1] = *(const float4*)&Wf[gb + 4];
    }

    for (int kt = 0; kt < CDIM; kt += 64) {
        __syncthreads();
#pragma unroll
        for (int it = 0; it < 4; ++it) {
            *(uint4*)&As[(row + 32 * it) * LSTR + c8s] =
                pack8(pa[it][0], pa[it][1]);
            *(uint4*)&Bs[(row + 32 * it) * LSTR + c8s] =
                pack8(pb[it][0], pb[it][1]);
        }
        __syncthreads();

        if (kt + 64 < CDIM) {
#pragma unroll
            for (int it = 0; it < 4; ++it) {
                size_t ga = (size_t)(m0 + row + 32 * it) * CDIM + kt + 64 + c8s;
                size_t gb = (size_t)(n0 + row + 32 * it) * CDIM + kt + 64 + c8s;
                pa[it][0] = *(const float4*)&Xf[ga];
                pa[it][1] = *(const float4*)&Xf[ga + 4];
                pb[it][0] = *(const float4*)&Wf[gb];
                pb[it][1] = *(const float4*)&Wf[gb + 4];
            }
        }

#pragma unroll
        for (int k = 0; k < 2; ++k) {
            bf16x8 af[4];
#pragma unroll
            for (int mi = 0; mi < 4; ++mi)
                af[mi] = *(const bf16x8*)
                    &As[(wr * 64 + mi * 16 + l15) * LSTR + quad * 8 + 32 * k];
#pragma unroll
            for (int ni = 0; ni < 4; ++ni) {
                bf16x8 bfr = *(const bf16x8*)
                    &Bs[(wc * 64 + ni * 16 + l15) * LSTR + quad * 8 + 32 * k];
#pragma unroll
                for (int mi = 0; mi < 4; ++mi)
                    acc[mi][ni] = __builtin_amdgcn_mfma_f32_16x16x32_bf16(
                        af[mi], bfr, acc[mi][ni], 0, 0, 0);
            }
        }
    }

    __syncthreads();   // all waves done reading As/Bs before overlay

    // Epilogue. C-layout: token row = wr*64+mi*16+quad*4+r,
    // feature col = wc*64+ni*16+l15. Wave's 64 cols = exactly one head.
    const int bi      = m0 >> 11;
    const int nbase   = (m0 & 2047) + wr * 64;
    const int colbase = n0 + wc * 64;
    const int sel     = colbase / CDIM;          // 0=q,1=k,2=v (wave-uniform)
    const int h       = (colbase % CDIM) >> 6;

    u16* Ew = S + wid * 64 * LSTR;     // wave-private 64x72 tile
    const int grow = lane >> 3;        // copy-out: 8 lanes cover one 128B row
    const int gc8  = (lane & 7) << 3;

    if (sel == 2) {
#pragma unroll
        for (int ni = 0; ni < 4; ++ni)
#pragma unroll
            for (int mi = 0; mi < 4; ++mi)
#pragma unroll
                for (int r = 0; r < 4; ++r)
                    Ew[(ni * 16 + l15) * LSTR + mi * 16 + quad * 4 + r] =
                        f2bf(acc[mi][ni][r]);
        u16* dst = Vb + (size_t)(bi * NH + h) * HD * NSEQ;   // [64][2048]
#pragma unroll
        for (int it = 0; it < 8; ++it) {
            int dd = grow + 8 * it;
            *(uint4*)&dst[(size_t)dd * NSEQ + nbase + gc8] =
                *(const uint4*)&Ew[dd * LSTR + gc8];
        }
    } else {
        u16* dst = ((sel == 0) ? Qb : Kb) + (size_t)(bi * NH + h) * NSEQ * HD;
        const float scl = (sel == 0) ? 0.125f : 1.0f;
#pragma unroll
        for (int ni = 0; ni < 4; ++ni) {
            int dd = ni * 16 + l15;
            float invf = expf(-0.14391156831212787f * (float)(dd & ~1));
#pragma unroll
            for (int mi = 0; mi < 4; ++mi) {
                f32x4 val = acc[mi][ni];
#pragma unroll
                for (int r = 0; r < 4; ++r) {
                    float e = val[r] * scl;
                    float p = __shfl_xor(e, 1);    // pair partner (col^1)
                    int n = nbase + mi * 16 + quad * 4 + r;
                    float sv, cv;
                    __sincosf((float)n * invf, &sv, &cv);
                    float o = (dd & 1) ? (e * cv + p * sv)
                                       : (e * cv - p * sv);
                    Ew[(mi * 16 + quad * 4 + r) * LSTR + dd] = f2bf(o);
                }
            }
        }
#pragma unroll
        for (int it = 0; it < 8; ++it) {
            int tr = grow + 8 * it;
            *(uint4*)&dst[(size_t)(nbase + tr) * HD + gc8] =
                *(const uint4*)&Ew[tr * LSTR + gc8];
        }
    }
}

// ---------------------------------------------------------------------------
// Kernel 2: flash attention, bf16 MFMA — R8 structure (empirical optimum of
// the tilings tested: R8 57.3us < R10 69us < R12 73.5us; MFMA busy time is
// identical ~9.9us across all three, the simpler structure wins on VALU/
// serialization overhead). S^T orientation (A=K-frag, B=Q-frag): lane holds
// 16 keys of ONE q-row -> in-lane softmax sums; fixed-max softmax (|s|<=~8,
// exp can't overflow); K/V double-buffered in LDS, ONE barrier per key-tile,
// register prefetch fills the other buffer while MFMAs run. 16 q-rows/wave,
// 64 q-rows/block, grid 32x24=768 = 3 blocks/CU balanced.
// ---------------------------------------------------------------------------
__global__ __launch_bounds__(256)
void attn_kernel(const u16* __restrict__ Qb, const u16* __restrict__ Kb,
                 const u16* __restrict__ Vt, u16* __restrict__ AO)
{
    __shared__ __align__(16) u16 Ks[2][64 * LSTR];
    __shared__ __align__(16) u16 Vs[2][64 * LSTR];   // [d][key]
    __shared__ __align__(16) u16 Ps[64 * LSTR];      // Q stage, then P tiles

    const int tid  = threadIdx.x;
    const int lane = tid & 63;
    const int wid  = tid >> 6;
    const int l15  = lane & 15;
    const int quad = lane >> 4;
    const int qt = blockIdx.x;      // 0..31
    const int bh = blockIdx.y;      // 0..23

    const u16* Qg = Qb + ((size_t)bh * NSEQ + qt * 64) * HD;
    const u16* Kg = Kb + (size_t)bh * NSEQ * HD;
    const u16* Vg = Vt + (size_t)bh * HD * NSEQ;   // [64][2048]

    const int row0 = tid >> 3, c8 = (tid & 7) << 3;   // rows 0..31
    const int row1 = row0 + 32;

    // stage Q (64x64) through Ps; stage kt=0 K/V into buffer 0
    *(uint4*)&Ps[row0 * LSTR + c8] = *(const uint4*)&Qg[row0 * HD + c8];
    *(uint4*)&Ps[row1 * LSTR + c8] = *(const uint4*)&Qg[row1 * HD + c8];
    *(uint4*)&Ks[0][row0 * LSTR + c8] = *(const uint4*)&Kg[(size_t)row0 * HD + c8];
    *(uint4*)&Ks[0][row1 * LSTR + c8] = *(const uint4*)&Kg[(size_t)row1 * HD + c8];
    *(uint4*)&Vs[0][row0 * LSTR + c8] = *(const uint4*)&Vg[(size_t)row0 * NSEQ + c8];
    *(uint4*)&Vs[0][row1 * LSTR + c8] = *(const uint4*)&Vg[(size_t)row1 * NSEQ + c8];
    __syncthreads();

    bf16x8 aq[2];
#pragma unroll
    for (int k = 0; k < 2; ++k)
        aq[k] = *(const bf16x8*)&Ps[(wid * 16 + l15) * LSTR + quad * 8 + 32 * k];

    float l_part = 0.f;       // per-lane partial: qrow = l15, 16 keys/tile
    f32x4 O[4];
#pragma unroll
    for (int t = 0; t < 4; ++t) O[t] = (f32x4){0.f, 0.f, 0.f, 0.f};

    u16* Pw = Ps + wid * 16 * LSTR;

    for (int kt = 0; kt < NSEQ / 64; ++kt) {
        const int cur = kt & 1;
        uint4 k0, k1, v0, v1;
        if (kt + 1 < NSEQ / 64) {
            k0 = *(const uint4*)&Kg[(size_t)((kt + 1) * 64 + row0) * HD + c8];
            k1 = *(const uint4*)&Kg[(size_t)((kt + 1) * 64 + row1) * HD + c8];
            v0 = *(const uint4*)&Vg[(size_t)row0 * NSEQ + (kt + 1) * 64 + c8];
            v1 = *(const uint4*)&Vg[(size_t)row1 * NSEQ + (kt + 1) * 64 + c8];
        }

        // S^T = K . Q^T : D[key=mt*16+quad*4+r][qrow=l15]
        f32x4 sacc[4];
#pragma unroll
        for (int mt = 0; mt < 4; ++mt) sacc[mt] = (f32x4){0.f, 0.f, 0.f, 0.f};
#pragma unroll
        for (int k = 0; k < 2; ++k) {
#pragma unroll
            for (int mt = 0; mt < 4; ++mt) {
                bf16x8 ak = *(const bf16x8*)
                    &Ks[cur][(mt * 16 + l15) * LSTR + quad * 8 + 32 * k];
                sacc[mt] = __builtin_amdgcn_mfma_f32_16x16x32_bf16(
                    ak, aq[k], sacc[mt], 0, 0, 0);
            }
        }

        // fixed-max softmax, all in-lane; pack 4 keys -> one b64 write
#pragma unroll
        for (int mt = 0; mt < 4; ++mt) {
            float e0 = __expf(sacc[mt][0]);
            float e1 = __expf(sacc[mt][1]);
            float e2 = __expf(sacc[mt][2]);
            float e3 = __expf(sacc[mt][3]);
            l_part += (e0 + e1) + (e2 + e3);
            ushort4v pk;
            pk.x = f2bf(e0); pk.y = f2bf(e1);
            pk.z = f2bf(e2); pk.w = f2bf(e3);
            *(ushort4v*)&Pw[l15 * LSTR + mt * 16 + quad * 4] = pk;
        }

        // O += P . V : A = P rows (m=qrow=l15 frag), B = Vt (d-major)
#pragma unroll
        for (int k = 0; k < 2; ++k) {
            bf16x8 ap = *(const bf16x8*)&Pw[l15 * LSTR + quad * 8 + 32 * k];
#pragma unroll
            for (int t = 0; t < 4; ++t) {
                bf16x8 bv = *(const bf16x8*)
                    &Vs[cur][(t * 16 + l15) * LSTR + quad * 8 + 32 * k];
                O[t] = __builtin_amdgcn_mfma_f32_16x16x32_bf16(
                    ap, bv, O[t], 0, 0, 0);
            }
        }

        if (kt + 1 < NSEQ / 64) {
            // fill the other buffer (its previous readers passed last barrier)
            *(uint4*)&Ks[cur ^ 1][row0 * LSTR + c8] = k0;
            *(uint4*)&Ks[cur ^ 1][row1 * LSTR + c8] = k1;
            *(uint4*)&Vs[cur ^ 1][row0 * LSTR + c8] = v0;
            *(uint4*)&Vs[cur ^ 1][row1 * LSTR + c8] = v1;
        }
        __syncthreads();   // single barrier per iteration
    }

    // finale: reduce l over quads (lanes l15, l15+16, l15+32, l15+48)
    float l = l_part + __shfl_xor(l_part, 16);
    l += __shfl_xor(l, 32);
    float inv[4];
#pragma unroll
    for (int r = 0; r < 4; ++r) inv[r] = 1.0f / __shfl(l, quad * 4 + r);

    const int b = bh / NH, h = bh % NH;
#pragma unroll
    for (int r = 0; r < 4; ++r) {
        size_t row = (size_t)b * NSEQ + qt * 64 + wid * 16 + quad * 4 + r;
#pragma unroll
        for (int t = 0; t < 4; ++t)
            AO[row * CDIM + h * HD + t * 16 + l15] = f2bf(O[t][r] * inv[r]);
    }
}

// ---------------------------------------------------------------------------
// Kernel 3: out = AO @ Wproj^T + bias, bf16 MFMA; Wproj read fp32 and
// converted during staging. Tiles 128x128x64, 4 waves 2x2.
// grid MUST be (32, 6): 768 cols / 128 per tile = 6 column tiles.
// ---------------------------------------------------------------------------
__global__ __launch_bounds__(256)
void proj_kernel(const u16* __restrict__ A, const float* __restrict__ Wf,
                 const float* __restrict__ bias, float* __restrict__ out)
{
    __shared__ __align__(16) u16 As[128 * LSTR];
    __shared__ __align__(16) u16 Bs[128 * LSTR];
    const int tid  = threadIdx.x;
    const int lane = tid & 63;
    const int wid  = tid >> 6;
    const int l15  = lane & 15;
    const int quad = lane >> 4;
    const int wr = wid >> 1, wc = wid & 1;
    const int m0 = blockIdx.x * 128;
    const int n0 = blockIdx.y * 128;

    f32x4 acc[4][4];
#pragma unroll
    for (int mi = 0; mi < 4; ++mi)
#pragma unroll
        for (int ni = 0; ni < 4; ++ni)
            acc[mi][ni] = (f32x4){0.f, 0.f, 0.f, 0.f};

    for (int kt = 0; kt < CDIM; kt += 64) {
        __syncthreads();
#pragma unroll
        for (int it = 0; it < 4; ++it) {
            int idx = tid + 256 * it;
            int row = idx >> 3, c8 = (idx & 7) << 3;
            *(uint4*)&As[row * LSTR + c8] =
                *(const uint4*)&A[(size_t)(m0 + row) * CDIM + kt + c8];
            size_t gb = (size_t)(n0 + row) * CDIM + kt + c8;
            float4 w0 = *(const float4*)&Wf[gb];
            float4 w1 = *(const float4*)&Wf[gb + 4];
            *(uint4*)&Bs[row * LSTR + c8] = pack8(w0, w1);
        }
        __syncthreads();
#pragma unroll
        for (int k = 0; k < 2; ++k) {
            bf16x8 af[4], bf[4];
#pragma unroll
            for (int mi = 0; mi < 4; ++mi)
                af[mi] = *(const bf16x8*)
                    &As[(wr * 64 + mi * 16 + l15) * LSTR + quad * 8 + 32 * k];
#pragma unroll
            for (int ni = 0; ni < 4; ++ni)
                bf[ni] = *(const bf16x8*)
                    &Bs[(wc * 64 + ni * 16 + l15) * LSTR + quad * 8 + 32 * k];
#pragma unroll
            for (int mi = 0; mi < 4; ++mi)
#pragma unroll
                for (int ni = 0; ni < 4; ++ni)
                    acc[mi][ni] = __builtin_amdgcn_mfma_f32_16x16x32_bf16(
                        af[mi], bf[ni], acc[mi][ni], 0, 0, 0);
        }
    }

#pragma unroll
    for (int ni = 0; ni < 4; ++ni) {
        int col = n0 + wc * 64 + ni * 16 + l15;
        float bb = bias[col];
#pragma unroll
        for (int mi = 0; mi < 4; ++mi) {
            int row = m0 + wr * 64 + mi * 16 + quad * 4;
#pragma unroll
            for (int r = 0; r < 4; ++r)
                out[(size_t)(row + r) * CDIM + col] = acc[mi][ni][r] + bb;
        }
    }
}

// ---------------------------------------------------------------------------
extern "C" void kernel_launch(void* const* d_in, const int* in_sizes, int n_in,
                              void* d_out, int out_size, void* d_ws,
                              size_t ws_size, hipStream_t stream)
{
    const float* X     = (const float*)d_in[0];   // [2, 2048, 768]
    const float* Wqkv  = (const float*)d_in[1];   // [2304, 768]
    const float* Wproj = (const float*)d_in[2];   // [768, 768]
    const float* bias  = (const float*)d_in[3];   // [768]
    float* out = (float*)d_out;                   // [2, 2048, 768]

    const size_t per_buf = (size_t)NB * NH * NSEQ * HD;   // 3145728
    u16* Qb  = (u16*)d_ws;
    u16* Kb  = Qb + per_buf;
    u16* Vb  = Kb + per_buf;                      // [B,H,64,N]
    u16* AOb = Vb + per_buf;                      // [4096, 768] bf16

    qkv_mfma_kernel<<<dim3(32, 18), 256, 0, stream>>>(X, Wqkv, Qb, Kb, Vb);
    attn_kernel<<<dim3(32, 24), 256, 0, stream>>>(Qb, Kb, Vb, AOb);
    proj_kernel<<<dim3(32, 6), 256, 0, stream>>>(AOb, Wproj, bias, out);
}